// Round 1
// baseline (1253.074 us; speedup 1.0000x reference)
//
#include <hip/hip_runtime.h>
#include <hip/hip_bf16.h>
#include <math.h>

#define BB 32
#define TT 4096
#define FF 1024
#define DD 1024
#define HH 16
#define DEPTH 64

// ws layout (floats):
// q      [B][D]      off 0         32768
// c      [B][H]      off 32768     512
// u      [B][H][F]   off 33280     524288
// logits [B][H][T]   off 557568    2097152   (becomes attn in-place)
// w      [B][H][F]   off 2654720   524288
// pooled [B][D]      off 3179008   32768
// total 3211776 floats = 12.25 MiB

// ---------------- q = state @ Wq + bq ----------------
__global__ __launch_bounds__(256) void qkern(const float* __restrict__ state,
                                             const float* __restrict__ Wq,
                                             const float* __restrict__ bq,
                                             float* __restrict__ q) {
    const int b = blockIdx.x;
    const int d = threadIdx.x * 4;
    const float* __restrict__ srow = state + b * 1024;
    float4 acc = make_float4(0.f, 0.f, 0.f, 0.f);
#pragma unroll 4
    for (int k = 0; k < 1024; ++k) {
        const float s = srow[k];
        const float4 wq = *reinterpret_cast<const float4*>(Wq + (size_t)k * DD + d);
        acc.x = fmaf(s, wq.x, acc.x);
        acc.y = fmaf(s, wq.y, acc.y);
        acc.z = fmaf(s, wq.z, acc.z);
        acc.w = fmaf(s, wq.w, acc.w);
    }
    const float4 bb = *reinterpret_cast<const float4*>(bq + d);
    acc.x += bb.x; acc.y += bb.y; acc.z += bb.z; acc.w += bb.w;
    *reinterpret_cast<float4*>(q + b * DD + d) = acc;
}

// ---------------- c[b,h] = bv_h . q_{b,h} ----------------
__global__ __launch_bounds__(512) void ckern(const float* __restrict__ q,
                                             const float* __restrict__ bv,
                                             float* __restrict__ c) {
    const int tid = threadIdx.x;   // = b*16 + h
    const int b = tid >> 4, h = tid & 15;
    float s = 0.f;
#pragma unroll
    for (int d = 0; d < DEPTH; ++d)
        s = fmaf(bv[h * DEPTH + d], q[b * DD + h * DEPTH + d], s);
    c[tid] = s;
}

// ---------------- u[b,h,f] = sum_d Wv[f, h*64+d] * q[b, h*64+d] ----------------
__global__ __launch_bounds__(256) void ukern(const float* __restrict__ Wv,
                                             const float* __restrict__ q,
                                             float* __restrict__ u) {
    const int h = blockIdx.x;            // 0..15
    const int f0 = blockIdx.y * 64;      // 0,64,...,960
    __shared__ float qs[BB][DEPTH];          // 8 KB
    __shared__ float wvs[DEPTH][DEPTH + 1];  // ~16.6 KB
    const int tid = threadIdx.x;
#pragma unroll
    for (int i = 0; i < 8; ++i) {
        const int idx = i * 256 + tid;   // 0..2047
        const int bq_ = idx >> 6, d = idx & 63;
        qs[bq_][d] = q[bq_ * DD + h * DEPTH + d];
    }
#pragma unroll
    for (int i = 0; i < 16; ++i) {
        const int idx = i * 256 + tid;   // 0..4095
        const int r = idx >> 6, d = idx & 63;
        wvs[r][d] = Wv[(size_t)(f0 + r) * DD + h * DEPTH + d];
    }
    __syncthreads();
    const int fl = tid & 63;
    const int bg = (tid >> 6) * 8;
    float acc[8] = {0.f, 0.f, 0.f, 0.f, 0.f, 0.f, 0.f, 0.f};
#pragma unroll 8
    for (int d = 0; d < 64; ++d) {
        const float wv = wvs[fl][d];
#pragma unroll
        for (int j = 0; j < 8; ++j) acc[j] = fmaf(wv, qs[bg + j][d], acc[j]);
    }
#pragma unroll
    for (int j = 0; j < 8; ++j)
        u[((size_t)(bg + j) * HH + h) * FF + f0 + fl] = acc[j];
}

// ---------------- logits[b,h,t] = (feat[b,t,:] . u[b,h,:] + c[b,h]) / 8 ----------------
__global__ __launch_bounds__(256) void logitskern(const float* __restrict__ feat,
                                                  const float* __restrict__ u,
                                                  const float* __restrict__ c,
                                                  float* __restrict__ logits) {
    const int b = blockIdx.y;
    const int t0 = blockIdx.x * 256;
    __shared__ float fs[256][33];   // ~33.8 KB, padded: compute reads hit distinct banks
    __shared__ float us[HH][33];
    const int tid = threadIdx.x;
    const int tx = tid & 63;
    const int h0 = (tid >> 6) * 4;
    float acc[4][4] = {};
    for (int fc = 0; fc < 32; ++fc) {
        const int f0 = fc * 32;
        __syncthreads();
        {   // stage 256 t-rows x 32 f
            const int f4 = (tid & 7) * 4;
            const int r0 = tid >> 3;
#pragma unroll
            for (int i = 0; i < 8; ++i) {
                const int row = r0 + i * 32;
                const float4 v = *reinterpret_cast<const float4*>(
                    feat + (size_t)(b * TT + t0 + row) * FF + f0 + f4);
                fs[row][f4 + 0] = v.x; fs[row][f4 + 1] = v.y;
                fs[row][f4 + 2] = v.z; fs[row][f4 + 3] = v.w;
            }
        }
        if (tid < 128) {   // stage 16 h x 32 f of u
            const int h = tid >> 3, f4 = (tid & 7) * 4;
            const float4 v = *reinterpret_cast<const float4*>(
                u + (size_t)(b * HH + h) * FF + f0 + f4);
            us[h][f4 + 0] = v.x; us[h][f4 + 1] = v.y;
            us[h][f4 + 2] = v.z; us[h][f4 + 3] = v.w;
        }
        __syncthreads();
#pragma unroll 8
        for (int ff = 0; ff < 32; ++ff) {
            const float a0 = fs[tx][ff],       a1 = fs[tx + 64][ff];
            const float a2 = fs[tx + 128][ff], a3 = fs[tx + 192][ff];
            const float u0 = us[h0][ff],     u1 = us[h0 + 1][ff];
            const float u2 = us[h0 + 2][ff], u3 = us[h0 + 3][ff];
            acc[0][0] = fmaf(a0, u0, acc[0][0]); acc[0][1] = fmaf(a0, u1, acc[0][1]);
            acc[0][2] = fmaf(a0, u2, acc[0][2]); acc[0][3] = fmaf(a0, u3, acc[0][3]);
            acc[1][0] = fmaf(a1, u0, acc[1][0]); acc[1][1] = fmaf(a1, u1, acc[1][1]);
            acc[1][2] = fmaf(a1, u2, acc[1][2]); acc[1][3] = fmaf(a1, u3, acc[1][3]);
            acc[2][0] = fmaf(a2, u0, acc[2][0]); acc[2][1] = fmaf(a2, u1, acc[2][1]);
            acc[2][2] = fmaf(a2, u2, acc[2][2]); acc[2][3] = fmaf(a2, u3, acc[2][3]);
            acc[3][0] = fmaf(a3, u0, acc[3][0]); acc[3][1] = fmaf(a3, u1, acc[3][1]);
            acc[3][2] = fmaf(a3, u2, acc[3][2]); acc[3][3] = fmaf(a3, u3, acc[3][3]);
        }
    }
#pragma unroll
    for (int k = 0; k < 4; ++k) {
        const float cc = c[b * HH + h0 + k];
#pragma unroll
        for (int j = 0; j < 4; ++j) {
            logits[(size_t)(b * HH + h0 + k) * TT + t0 + tx + j * 64] =
                (acc[j][k] + cc) * 0.125f;
        }
    }
}

// ---------------- softmax over t, in place ----------------
__global__ __launch_bounds__(256) void softmaxkern(float* __restrict__ logits) {
    const int bh = blockIdx.x;
    float* __restrict__ row = logits + (size_t)bh * TT;
    const int tid = threadIdx.x;
    float v[16];
#pragma unroll
    for (int i = 0; i < 16; ++i) v[i] = row[tid + i * 256];
    float m = -1e30f;
#pragma unroll
    for (int i = 0; i < 16; ++i) m = fmaxf(m, v[i]);
#pragma unroll
    for (int off = 32; off; off >>= 1) m = fmaxf(m, __shfl_down(m, off, 64));
    __shared__ float redm[4];
    if ((tid & 63) == 0) redm[tid >> 6] = m;
    __syncthreads();
    m = fmaxf(fmaxf(redm[0], redm[1]), fmaxf(redm[2], redm[3]));
    float s = 0.f;
#pragma unroll
    for (int i = 0; i < 16; ++i) { v[i] = __expf(v[i] - m); s += v[i]; }
#pragma unroll
    for (int off = 32; off; off >>= 1) s += __shfl_down(s, off, 64);
    __shared__ float reds[4];
    if ((tid & 63) == 0) reds[tid >> 6] = s;
    __syncthreads();
    s = reds[0] + reds[1] + reds[2] + reds[3];
    const float inv = 1.f / s;
#pragma unroll
    for (int i = 0; i < 16; ++i) row[tid + i * 256] = v[i] * inv;
}

// ---------------- w[b,h,f] += sum_t attn[b,h,t] * feat[b,t,f] ----------------
__global__ __launch_bounds__(256) void wkern(const float* __restrict__ feat,
                                             const float* __restrict__ attn,
                                             float* __restrict__ w) {
    const int sp = blockIdx.x;   // 0..7 t-split
    const int b = blockIdx.y;
    const int t0 = sp * 512;
    __shared__ float as[HH][512];   // 32 KB
    const int tid = threadIdx.x;
#pragma unroll
    for (int i = 0; i < 8; ++i) {
        const int idx = i * 256 + tid;           // float4 index 0..2047
        const int h = idx >> 7, t4 = (idx & 127) * 4;
        const float4 v = *reinterpret_cast<const float4*>(
            attn + (size_t)(b * HH + h) * TT + t0 + t4);
        *reinterpret_cast<float4*>(&as[h][t4]) = v;
    }
    __syncthreads();
    const int f = tid * 4;
    float4 acc[HH];
#pragma unroll
    for (int h = 0; h < HH; ++h) acc[h] = make_float4(0.f, 0.f, 0.f, 0.f);
#pragma unroll 2
    for (int tl = 0; tl < 512; ++tl) {
        const float4 x = *reinterpret_cast<const float4*>(
            feat + (size_t)(b * TT + t0 + tl) * FF + f);
#pragma unroll
        for (int h = 0; h < HH; ++h) {
            const float a = as[h][tl];
            acc[h].x = fmaf(a, x.x, acc[h].x);
            acc[h].y = fmaf(a, x.y, acc[h].y);
            acc[h].z = fmaf(a, x.z, acc[h].z);
            acc[h].w = fmaf(a, x.w, acc[h].w);
        }
    }
#pragma unroll
    for (int h = 0; h < HH; ++h) {
        float* dst = w + (size_t)(b * HH + h) * FF + f;
        atomicAdd(dst + 0, acc[h].x);
        atomicAdd(dst + 1, acc[h].y);
        atomicAdd(dst + 2, acc[h].z);
        atomicAdd(dst + 3, acc[h].w);
    }
}

// ---------------- pooled[b, h*64+dd] = w[b,h,:] . Wv[:, h*64+dd] + bv ----------------
__global__ __launch_bounds__(256) void outkern(const float* __restrict__ w,
                                               const float* __restrict__ Wv,
                                               const float* __restrict__ bv,
                                               float* __restrict__ pooled) {
    const int bh = blockIdx.x;
    const int b = bh >> 4, h = bh & 15;
    __shared__ float ws_[FF];
    const int tid = threadIdx.x;
#pragma unroll
    for (int i = 0; i < 4; ++i) ws_[i * 256 + tid] = w[(size_t)bh * FF + i * 256 + tid];
    __syncthreads();
    const int dd = tid & 63;
    const int fq = tid >> 6;   // 0..3
    float acc = 0.f;
#pragma unroll 8
    for (int i = 0; i < 256; ++i) {
        const int f_ = fq * 256 + i;
        acc = fmaf(ws_[f_], Wv[(size_t)f_ * DD + h * DEPTH + dd], acc);
    }
    __shared__ float part[4][64];
    part[fq][dd] = acc;
    __syncthreads();
    if (tid < 64) {
        const float r = part[0][dd] + part[1][dd] + part[2][dd] + part[3][dd];
        pooled[b * DD + h * DEPTH + dd] = r + bv[h * DEPTH + dd];
    }
}

// ---------------- out = pooled @ Wd + bd ----------------
__global__ __launch_bounds__(256) void finalkern(const float* __restrict__ pooled,
                                                 const float* __restrict__ Wd,
                                                 const float* __restrict__ bd,
                                                 float* __restrict__ out) {
    const int b = blockIdx.x;
    const int n = threadIdx.x * 4;
    const float* __restrict__ prow = pooled + b * DD;
    float4 acc = make_float4(0.f, 0.f, 0.f, 0.f);
#pragma unroll 4
    for (int k = 0; k < DD; ++k) {
        const float p = prow[k];
        const float4 wd = *reinterpret_cast<const float4*>(Wd + (size_t)k * DD + n);
        acc.x = fmaf(p, wd.x, acc.x);
        acc.y = fmaf(p, wd.y, acc.y);
        acc.z = fmaf(p, wd.z, acc.z);
        acc.w = fmaf(p, wd.w, acc.w);
    }
    const float4 bb = *reinterpret_cast<const float4*>(bd + n);
    acc.x += bb.x; acc.y += bb.y; acc.z += bb.z; acc.w += bb.w;
    *reinterpret_cast<float4*>(out + b * DD + n) = acc;
}

extern "C" void kernel_launch(void* const* d_in, const int* in_sizes, int n_in,
                              void* d_out, int out_size, void* d_ws, size_t ws_size,
                              hipStream_t stream) {
    const float* feat  = (const float*)d_in[0];
    const float* state = (const float*)d_in[1];
    const float* Wq    = (const float*)d_in[2];
    const float* bq    = (const float*)d_in[3];
    const float* Wv    = (const float*)d_in[4];
    const float* bv    = (const float*)d_in[5];
    const float* Wd    = (const float*)d_in[6];
    const float* bd    = (const float*)d_in[7];
    float* out = (float*)d_out;
    float* ws = (float*)d_ws;

    float* q      = ws;
    float* c      = ws + 32768;
    float* u      = ws + 33280;
    float* logits = ws + 557568;
    float* w      = ws + 2654720;
    float* pooled = ws + 3179008;

    hipMemsetAsync(w, 0, 524288 * sizeof(float), stream);
    qkern<<<BB, 256, 0, stream>>>(state, Wq, bq, q);
    ckern<<<1, 512, 0, stream>>>(q, bv, c);
    ukern<<<dim3(HH, FF / 64), 256, 0, stream>>>(Wv, q, u);
    logitskern<<<dim3(TT / 256, BB), 256, 0, stream>>>(feat, u, c, logits);
    softmaxkern<<<BB * HH, 256, 0, stream>>>(logits);
    wkern<<<dim3(8, BB), 256, 0, stream>>>(feat, logits, w);
    outkern<<<BB * HH, 256, 0, stream>>>(w, Wv, bv, pooled);
    finalkern<<<BB, 256, 0, stream>>>(pooled, Wd, bd, out);
}

// Round 2
// 1149.760 us; speedup vs baseline: 1.0899x; 1.0899x over previous
//
#include <hip/hip_runtime.h>
#include <hip/hip_bf16.h>
#include <math.h>

#define BB 32
#define TT 4096
#define FF 1024
#define DD 1024
#define HH 16
#define DEPTH 64

// ws layout (floats):
// q      [B][D]      off 0         32768
// c      [B][H]      off 32768     512
// u      [B][H][F]   off 33280     524288
// logits [B][H][T]   off 557568    2097152   (becomes attn in-place)
// w      [B][H][F]   off 2654720   524288
// pooled [B][D]      off 3179008   32768

// ---------------- Y[b,n] = X[b,:] @ W + bias  (32x1024x1024 GEMM) ----------------
// grid (8 n-chunks, 32 b), 256 thr: 32 f4-columns x 8-way k-split, LDS reduce.
__global__ __launch_bounds__(256) void smallgemm(const float* __restrict__ X,
                                                 const float* __restrict__ W,
                                                 const float* __restrict__ bias,
                                                 float* __restrict__ Y) {
    const int b = blockIdx.y;
    const int n = blockIdx.x * 128 + (threadIdx.x & 31) * 4;
    const int kg = threadIdx.x >> 5;           // 0..7
    const float* __restrict__ x = X + b * DD + kg * 128;
    float4 acc = make_float4(0.f, 0.f, 0.f, 0.f);
#pragma unroll 4
    for (int k = 0; k < 128; ++k) {
        const float s = x[k];
        const float4 wr = *reinterpret_cast<const float4*>(W + (size_t)(kg * 128 + k) * DD + n);
        acc.x = fmaf(s, wr.x, acc.x);
        acc.y = fmaf(s, wr.y, acc.y);
        acc.z = fmaf(s, wr.z, acc.z);
        acc.w = fmaf(s, wr.w, acc.w);
    }
    __shared__ float4 red[8][33];
    red[kg][threadIdx.x & 31] = acc;
    __syncthreads();
    if (threadIdx.x < 32) {
        float4 r = red[0][threadIdx.x];
#pragma unroll
        for (int g = 1; g < 8; ++g) {
            const float4 p = red[g][threadIdx.x];
            r.x += p.x; r.y += p.y; r.z += p.z; r.w += p.w;
        }
        const int nn = blockIdx.x * 128 + threadIdx.x * 4;
        const float4 bb = *reinterpret_cast<const float4*>(bias + nn);
        r.x += bb.x; r.y += bb.y; r.z += bb.z; r.w += bb.w;
        *reinterpret_cast<float4*>(Y + b * DD + nn) = r;
    }
}

// ---------------- c[b,h] = bv_h . q_{b,h} ----------------
__global__ __launch_bounds__(512) void ckern(const float* __restrict__ q,
                                             const float* __restrict__ bv,
                                             float* __restrict__ c) {
    const int tid = threadIdx.x;   // = b*16 + h
    const int b = tid >> 4, h = tid & 15;
    float s = 0.f;
#pragma unroll
    for (int d = 0; d < DEPTH; ++d)
        s = fmaf(bv[h * DEPTH + d], q[b * DD + h * DEPTH + d], s);
    c[tid] = s;
}

// ---------------- u[b,h,f] = sum_d Wv[f, h*64+d] * q[b, h*64+d] ----------------
__global__ __launch_bounds__(256) void ukern(const float* __restrict__ Wv,
                                             const float* __restrict__ q,
                                             float* __restrict__ u) {
    const int h = blockIdx.x;            // 0..15
    const int f0 = blockIdx.y * 64;      // 0,64,...,960
    __shared__ float qs[BB][DEPTH];
    __shared__ float wvs[DEPTH][DEPTH + 1];
    const int tid = threadIdx.x;
#pragma unroll
    for (int i = 0; i < 8; ++i) {
        const int idx = i * 256 + tid;
        const int bq_ = idx >> 6, d = idx & 63;
        qs[bq_][d] = q[bq_ * DD + h * DEPTH + d];
    }
#pragma unroll
    for (int i = 0; i < 16; ++i) {
        const int idx = i * 256 + tid;
        const int r = idx >> 6, d = idx & 63;
        wvs[r][d] = Wv[(size_t)(f0 + r) * DD + h * DEPTH + d];
    }
    __syncthreads();
    const int fl = tid & 63;
    const int bg = (tid >> 6) * 8;
    float acc[8] = {0.f, 0.f, 0.f, 0.f, 0.f, 0.f, 0.f, 0.f};
#pragma unroll 8
    for (int d = 0; d < 64; ++d) {
        const float wv = wvs[fl][d];
#pragma unroll
        for (int j = 0; j < 8; ++j) acc[j] = fmaf(wv, qs[bg + j][d], acc[j]);
    }
#pragma unroll
    for (int j = 0; j < 8; ++j)
        u[((size_t)(bg + j) * HH + h) * FF + f0 + fl] = acc[j];
}

// ---------------- logits[b,h,t] = (feat[b,t,:] . u[b,h,:] + c[b,h]) / 8 ----------------
// 512 blocks (16 t-tiles x 32 b). All LDS traffic via ds_read_b128; u-frag in regs.
__global__ __launch_bounds__(256) void logitskern(const float* __restrict__ feat,
                                                  const float* __restrict__ u,
                                                  const float* __restrict__ c,
                                                  float* __restrict__ logits) {
    const int b = blockIdx.y;
    const int t0 = blockIdx.x * 256;
    __shared__ float fs[256][36];   // pad 36: float4-aligned, 8-phase conflict-free
    __shared__ float us[HH][32];
    const int tid = threadIdx.x;
    const int tx = tid & 63;
    const int h0 = (tid >> 6) * 4;
    const int r0 = tid >> 3;
    const int f4 = (tid & 7) * 4;
    float acc[4][4] = {};
    for (int fc = 0; fc < 32; ++fc) {
        const int f0 = fc * 32;
        __syncthreads();
#pragma unroll
        for (int i = 0; i < 8; ++i) {
            const int row = r0 + i * 32;
            const float4 v = *reinterpret_cast<const float4*>(
                feat + (size_t)(b * TT + t0 + row) * FF + f0 + f4);
            *reinterpret_cast<float4*>(&fs[row][f4]) = v;
        }
        if (tid < 128) {
            const int h = tid >> 3;
            const float4 v = *reinterpret_cast<const float4*>(
                u + (size_t)(b * HH + h) * FF + f0 + f4);
            *reinterpret_cast<float4*>(&us[h][f4]) = v;
        }
        __syncthreads();
#pragma unroll
        for (int g = 0; g < 8; ++g) {
            float4 uu[4];
#pragma unroll
            for (int j = 0; j < 4; ++j)
                uu[j] = *reinterpret_cast<const float4*>(&us[h0 + j][g * 4]);
#pragma unroll
            for (int k = 0; k < 4; ++k) {
                const float4 a = *reinterpret_cast<const float4*>(&fs[tx + k * 64][g * 4]);
#pragma unroll
                for (int j = 0; j < 4; ++j) {
                    acc[k][j] = fmaf(a.x, uu[j].x, acc[k][j]);
                    acc[k][j] = fmaf(a.y, uu[j].y, acc[k][j]);
                    acc[k][j] = fmaf(a.z, uu[j].z, acc[k][j]);
                    acc[k][j] = fmaf(a.w, uu[j].w, acc[k][j]);
                }
            }
        }
    }
#pragma unroll
    for (int j = 0; j < 4; ++j) {
        const float cc = c[b * HH + h0 + j];
#pragma unroll
        for (int k = 0; k < 4; ++k) {
            logits[(size_t)(b * HH + h0 + j) * TT + t0 + tx + k * 64] =
                (acc[k][j] + cc) * 0.125f;
        }
    }
}

// ---------------- softmax over t, in place ----------------
__global__ __launch_bounds__(256) void softmaxkern(float* __restrict__ logits) {
    const int bh = blockIdx.x;
    float* __restrict__ row = logits + (size_t)bh * TT;
    const int tid = threadIdx.x;
    float v[16];
#pragma unroll
    for (int i = 0; i < 16; ++i) v[i] = row[tid + i * 256];
    float m = -1e30f;
#pragma unroll
    for (int i = 0; i < 16; ++i) m = fmaxf(m, v[i]);
#pragma unroll
    for (int off = 32; off; off >>= 1) m = fmaxf(m, __shfl_down(m, off, 64));
    __shared__ float redm[4];
    if ((tid & 63) == 0) redm[tid >> 6] = m;
    __syncthreads();
    m = fmaxf(fmaxf(redm[0], redm[1]), fmaxf(redm[2], redm[3]));
    float s = 0.f;
#pragma unroll
    for (int i = 0; i < 16; ++i) { v[i] = __expf(v[i] - m); s += v[i]; }
#pragma unroll
    for (int off = 32; off; off >>= 1) s += __shfl_down(s, off, 64);
    __shared__ float reds[4];
    if ((tid & 63) == 0) reds[tid >> 6] = s;
    __syncthreads();
    s = reds[0] + reds[1] + reds[2] + reds[3];
    const float inv = 1.f / s;
#pragma unroll
    for (int i = 0; i < 16; ++i) row[tid + i * 256] = v[i] * inv;
}

// ---------------- w[b,h,f] = sum_t attn[b,h,t] * feat[b,t,f] ----------------
// 512 blocks (16 f-chunks x 32 b). Lane = (h, f-subgroup): per t-step just
// 1 broadcast ds_read_b32 + 1 coalesced 64B global load + 4 FMA. No atomics:
// each block owns disjoint f-range, full t accumulated in registers.
__global__ __launch_bounds__(256) void wkern(const float* __restrict__ feat,
                                             const float* __restrict__ attn,
                                             float* __restrict__ w) {
    const int fc = blockIdx.x;   // 0..15
    const int b = blockIdx.y;
    const int tid = threadIdx.x;
    const int wv = tid >> 6;
    const int lane = tid & 63;
    const int h = lane >> 2;
    const int fg = lane & 3;
    const int f = fc * 64 + wv * 16 + fg * 4;
    __shared__ float as[HH][516];   // pad 4: aligned float4 writes, <=2-way read alias
    float4 acc = make_float4(0.f, 0.f, 0.f, 0.f);
    const float* __restrict__ fbase = feat + (size_t)b * TT * FF + f;
    for (int tc = 0; tc < 8; ++tc) {
        const int t0 = tc * 512;
        __syncthreads();
#pragma unroll
        for (int i = 0; i < 8; ++i) {
            const int idx = i * 256 + tid;
            const int hh = idx >> 7, t4 = (idx & 127) * 4;
            *reinterpret_cast<float4*>(&as[hh][t4]) =
                *reinterpret_cast<const float4*>(attn + (size_t)(b * HH + hh) * TT + t0 + t4);
        }
        __syncthreads();
#pragma unroll 8
        for (int s = 0; s < 512; ++s) {
            const float a = as[h][s];
            const float4 x = *reinterpret_cast<const float4*>(fbase + (size_t)(t0 + s) * FF);
            acc.x = fmaf(a, x.x, acc.x);
            acc.y = fmaf(a, x.y, acc.y);
            acc.z = fmaf(a, x.z, acc.z);
            acc.w = fmaf(a, x.w, acc.w);
        }
    }
    *reinterpret_cast<float4*>(w + ((size_t)b * HH + h) * FF + f) = acc;
}

// ---------------- pooled[b, h*64+dd] = w[b,h,:] . Wv[:, h*64+dd] + bv ----------------
__global__ __launch_bounds__(256) void outkern(const float* __restrict__ w,
                                               const float* __restrict__ Wv,
                                               const float* __restrict__ bv,
                                               float* __restrict__ pooled) {
    const int bh = blockIdx.x;
    const int b = bh >> 4, h = bh & 15;
    __shared__ float ws_[FF];
    const int tid = threadIdx.x;
#pragma unroll
    for (int i = 0; i < 4; ++i) ws_[i * 256 + tid] = w[(size_t)bh * FF + i * 256 + tid];
    __syncthreads();
    const int dd = tid & 63;
    const int fq = tid >> 6;   // 0..3
    float acc = 0.f;
#pragma unroll 8
    for (int i = 0; i < 256; ++i) {
        const int f_ = fq * 256 + i;
        acc = fmaf(ws_[f_], Wv[(size_t)f_ * DD + h * DEPTH + dd], acc);
    }
    __shared__ float part[4][64];
    part[fq][dd] = acc;
    __syncthreads();
    if (tid < 64) {
        const float r = part[0][dd] + part[1][dd] + part[2][dd] + part[3][dd];
        pooled[b * DD + h * DEPTH + dd] = r + bv[h * DEPTH + dd];
    }
}

extern "C" void kernel_launch(void* const* d_in, const int* in_sizes, int n_in,
                              void* d_out, int out_size, void* d_ws, size_t ws_size,
                              hipStream_t stream) {
    const float* feat  = (const float*)d_in[0];
    const float* state = (const float*)d_in[1];
    const float* Wq    = (const float*)d_in[2];
    const float* bq    = (const float*)d_in[3];
    const float* Wv    = (const float*)d_in[4];
    const float* bv    = (const float*)d_in[5];
    const float* Wd    = (const float*)d_in[6];
    const float* bd    = (const float*)d_in[7];
    float* out = (float*)d_out;
    float* ws = (float*)d_ws;

    float* q      = ws;
    float* c      = ws + 32768;
    float* u      = ws + 33280;
    float* logits = ws + 557568;
    float* w      = ws + 2654720;
    float* pooled = ws + 3179008;

    smallgemm<<<dim3(8, BB), 256, 0, stream>>>(state, Wq, bq, q);
    ckern<<<1, 512, 0, stream>>>(q, bv, c);
    ukern<<<dim3(HH, FF / 64), 256, 0, stream>>>(Wv, q, u);
    logitskern<<<dim3(TT / 256, BB), 256, 0, stream>>>(feat, u, c, logits);
    softmaxkern<<<BB * HH, 256, 0, stream>>>(logits);
    wkern<<<dim3(HH, BB), 256, 0, stream>>>(feat, logits, w);
    outkern<<<BB * HH, 256, 0, stream>>>(w, Wv, bv, pooled);
    smallgemm<<<dim3(8, BB), 256, 0, stream>>>(pooled, Wd, bd, out);
}